// Round 11
// baseline (218.541 us; speedup 1.0000x reference)
//
#include <hip/hip_runtime.h>

// ---------------------------------------------------------------------------
// QuantizedShaper: B=256, L=8192, DIM=256, NPAT=64, HIST=32, WIN=8, T=1024.
//
// SINGLE-KERNEL version (R11): the W2/bias2 precompute (former separate
// kernel) is fused as a per-block LDS prologue (~4 us of redundant compute,
// weights L2-resident) to eliminate the second launch + inter-kernel gap
// (~60 us/round of non-shaper time observed R1-R10).
//
// Count-space scan (validated R5/R8/R10, absmax 0.0):
//   U_t[p] = (relu6(score_t[p]) - av0[p]) + t/64   (fill waves)
//   v_t = U_t - cnt_t,  cnt += onehot(win), win = argmax v
// Scan step body identical to R10 (measured 251 cyc/step):
//   vA = U[i+1]-C; vB = vA-1; 6x fused dpp-max; readlane; e=(v==gmax);
//   C/v cndmask; winner via ballot/ffs SALU-packed 8b x8 per u64.
// ---------------------------------------------------------------------------

constexpr int Bb = 256, Ll = 8192, DIMc = 256, NPAT = 64, HIST = 32, WINc = 8;
constexpr int Tt = Ll / WINc;   // 1024
constexpr int TC = 32;          // t-chunk
constexpr int NC = Tt / TC;     // 32 chunks
constexpr float CINV = 1.0f / 64.0f;

#define DPP_STAGE(m, ctrl, rmask)                                              \
  (m) = fmaxf((m), __int_as_float(__builtin_amdgcn_update_dpp(                 \
            __float_as_int(m), __float_as_int(m), (ctrl), (rmask), 0xF, false)))

#define DPP_ADDF(s, ctrl, rmask)                                               \
  do {                                                                         \
    int _si = __float_as_int(s);                                               \
    int _ti = __builtin_amdgcn_update_dpp(_si, _si, (ctrl), (rmask), 0xF, false); \
    (s) += __int_as_float(_ti);                                                \
  } while (0)

__global__ __launch_bounds__(256) void shaper_kernel(
    const float* __restrict__ x, const float* __restrict__ avg_init,
    const float* __restrict__ conv_w, const float* __restrict__ conv_b,
    const float* __restrict__ keys_w, const float* __restrict__ shapes_w,
    float* __restrict__ out) {
  __shared__ __align__(16) float xpad[HIST - 1 + Ll + 1];
  __shared__ float scb[2][TC * NPAT];
  __shared__ unsigned long long idxp[NC * 4];  // 8 winners per u64
  __shared__ float shp[WINc * NPAT];
  __shared__ __align__(16) float w2[8][NPAT][4];  // [h4][p][h%4]
  __shared__ float bias2[NPAT];

  const int b    = blockIdx.x;
  const int tid  = threadIdx.x;
  const int wid  = tid >> 6;
  const int lane = tid & 63;
  const float* xrow = x + (size_t)b * Ll;

  // ---- stage x (left-padded) + shapes into LDS ----
  if (tid < HIST - 1) xpad[tid] = 0.f;
  {
    const float4* xv4 = (const float4*)xrow;
#pragma unroll
    for (int k = 0; k < 8; ++k) {
      int i4 = k * 256 + tid;
      float4 v = xv4[i4];
      float* dst = xpad + HIST - 1 + i4 * 4;
      dst[0] = v.x; dst[1] = v.y; dst[2] = v.z; dst[3] = v.w;
    }
  }
  for (int i = tid; i < WINc * NPAT; i += 256) shp[i] = shapes_w[i];

  // ---- W2 prologue: 64x32 entries, 8 per thread; W2[p,h]=sum_d kw[p,d]cw[d,h]
#pragma unroll
  for (int e = 0; e < 8; ++e) {
    int idx = e * 256 + tid;
    int p = idx >> 5, h = idx & 31;
    const float* kwp = keys_w + (size_t)p * DIMc;
    const float* cwh = conv_w + h;
    float acc = 0.f;
#pragma unroll 8
    for (int d = 0; d < DIMc; ++d) acc = fmaf(kwp[d], cwh[d * HIST], acc);
    w2[h >> 2][p][h & 3] = acc;
  }
  if (tid < NPAT) {
    const float* kwp = keys_w + (size_t)tid * DIMc;
    float acc = 0.f;
#pragma unroll 8
    for (int d = 0; d < DIMc; ++d) acc = fmaf(kwp[d], conv_b[d], acc);
    bias2[tid] = acc;
  }

  // ---- av0 via DPP-sum butterfly (all waves; validated R5/R8/R10) ----
  float av0;
  {
    float s = avg_init[(size_t)b * NPAT + lane];
    float t = s;
    DPP_ADDF(t, 0xB1, 0xF);
    DPP_ADDF(t, 0x4E, 0xF);
    DPP_ADDF(t, 0x141, 0xF);
    DPP_ADDF(t, 0x140, 0xF);
    DPP_ADDF(t, 0x142, 0xA);
    DPP_ADDF(t, 0x143, 0xC);   // lane63 = total
    float tot = __int_as_float(__builtin_amdgcn_readlane(__float_as_int(t), 63));
    av0 = s - tot * CINV;
  }
  __syncthreads();

  // ---- per-role setup (w2v from LDS) ----
  float4 w2v[8];
  float  b2 = 0.f;
  if (wid > 0) {
    const float4* w2g = (const float4*)w2;
#pragma unroll
    for (int h4 = 0; h4 < 8; ++h4) w2v[h4] = w2g[h4 * 64 + lane];
    b2 = bias2[lane];
  }

  // fill chunk c: sb[t][p] = (relu6(score) - av0[p]) + tglob/64  (== U_t[p])
  auto fill = [&](int c, float* __restrict__ sb) {
    int base = c * TC;
    for (int tl = wid - 1; tl < TC; tl += 3) {
      int t = base + tl;
      const float4* xw = (const float4*)(xpad + t * WINc);  // 32B-aligned
      float acc = b2;
#pragma unroll
      for (int h4 = 0; h4 < 8; ++h4) {
        float4 xv = xw[h4];
        float4 wv = w2v[h4];
        acc = fmaf(xv.x, wv.x, acc);
        acc = fmaf(xv.y, wv.y, acc);
        acc = fmaf(xv.z, wv.z, acc);
        acc = fmaf(xv.w, wv.w, acc);
      }
      float sc = fminf(fmaxf(acc, 0.f), 6.f);
      sb[tl * NPAT + lane] = (sc - av0) + (float)t * CINV;
    }
  };

  // ---- scan state (wave 0): C = win count (starts 0), across chunks ----
  float C = 0.f;

  auto scan_chunk = [&](const float* __restrict__ sb, int cidx) {
    float U[TC];
#pragma unroll
    for (int i = 0; i < TC; ++i) U[i] = sb[i * NPAT + lane];
    unsigned long long pk0 = 0, pk1 = 0, pk2 = 0, pk3 = 0;
    float v = U[0] - C;
#pragma unroll
    for (int i = 0; i < TC; ++i) {
      float vA = 0.f, vB = 0.f;
      if (i + 1 < TC) { vA = U[i + 1] - C; vB = vA - 1.0f; }
      float m = v;
      DPP_STAGE(m, 0xB1, 0xF);   // xor1
      DPP_STAGE(m, 0x4E, 0xF);   // xor2
      DPP_STAGE(m, 0x141, 0xF);  // xor4 (row_half_mirror)
      DPP_STAGE(m, 0x140, 0xF);  // xor8 (row_mirror) -> row16 max
      DPP_STAGE(m, 0x142, 0xA);  // row_bcast15 -> rows 1,3
      DPP_STAGE(m, 0x143, 0xC);  // row_bcast31 -> rows 2,3; lane63 = gmax
      float gmax = __int_as_float(
          __builtin_amdgcn_readlane(__float_as_int(m), 63));
      bool e = (v == gmax);             // all-maximal (tie-free, R6-R10)
      float C1 = C + 1.0f;
      // off-cycle: first-index winner, SALU-packed (8 bits each)
      unsigned long long mk = __ballot(e);
      unsigned long long w = (unsigned long long)(__ffsll(mk) - 1);
      if (i < 8)       pk0 |= w << (8 * (i & 7));
      else if (i < 16) pk1 |= w << (8 * (i & 7));
      else if (i < 24) pk2 |= w << (8 * (i & 7));
      else             pk3 |= w << (8 * (i & 7));
      C = e ? C1 : C;
      if (i + 1 < TC) v = e ? vB : vA;
    }
    if (lane == 0) {
      idxp[cidx * 4 + 0] = pk0;
      idxp[cidx * 4 + 1] = pk1;
      idxp[cidx * 4 + 2] = pk2;
      idxp[cidx * 4 + 3] = pk3;
    }
  };

  // ---- pipeline: wave0 scans chunk c, waves1-3 fill chunk c+1 ----
  if (wid > 0) fill(0, scb[0]);
  __syncthreads();

  for (int c = 0; c < NC; ++c) {
    if (wid == 0) {
      scan_chunk(scb[c & 1], c);
    } else if (c + 1 < NC) {
      fill(c + 1, scb[(c + 1) & 1]);
    }
    __syncthreads();
  }

  // ---- epilogue: out[b,l] = relu(shapes[l&7, idx[l>>3]] - x[b,l]) ----
  float4* outv = (float4*)(out + (size_t)b * Ll);
#pragma unroll
  for (int k = 0; k < 8; ++k) {
    int i4 = k * 256 + tid;
    int l0 = i4 * 4;
    int t  = l0 >> 3;
    int w0 = l0 & 7;
    int p  = (int)((idxp[t >> 3] >> (8 * (t & 7))) & 63ull);
    float4 o;
    o.x = fmaxf(shp[(w0 + 0) * NPAT + p] - xpad[HIST - 1 + l0 + 0], 0.f);
    o.y = fmaxf(shp[(w0 + 1) * NPAT + p] - xpad[HIST - 1 + l0 + 1], 0.f);
    o.z = fmaxf(shp[(w0 + 2) * NPAT + p] - xpad[HIST - 1 + l0 + 2], 0.f);
    o.w = fmaxf(shp[(w0 + 3) * NPAT + p] - xpad[HIST - 1 + l0 + 3], 0.f);
    outv[i4] = o;
  }
}

extern "C" void kernel_launch(void* const* d_in, const int* in_sizes, int n_in,
                              void* d_out, int out_size, void* d_ws, size_t ws_size,
                              hipStream_t stream) {
  const float* x        = (const float*)d_in[0];
  const float* avg_init = (const float*)d_in[1];
  const float* conv_w   = (const float*)d_in[2];
  const float* conv_b   = (const float*)d_in[3];
  const float* keys_w   = (const float*)d_in[4];
  const float* shapes_w = (const float*)d_in[5];

  shaper_kernel<<<Bb, 256, 0, stream>>>(x, avg_init, conv_w, conv_b, keys_w,
                                        shapes_w, (float*)d_out);
}

// Round 12
// 170.044 us; speedup vs baseline: 1.2852x; 1.2852x over previous
//
#include <hip/hip_runtime.h>

// ---------------------------------------------------------------------------
// QuantizedShaper: B=256, L=8192, DIM=256, NPAT=64, HIST=32, WIN=8, T=1024.
//
// R12 = exact revert to R10 (best measured: 170.5 us total, 107 us dispatch).
// R11's fused W2 prologue regressed (latency-bound global loads, +60 us);
// two-kernel layout costs only ~15 us over the 48 us fixed harness overhead.
//
// Count-space scan (validated R5/R8/R10, absmax 0.0):
//   U_t[p] = (relu6(score_t[p]) - av0[p]) + t/64   (fill waves)
//   v_t = U_t - cnt_t,  cnt += onehot(win), win = argmax v
// Minimal-issue step body (measured ~251 cyc/step):
//   vA = U[i+1]-C; vB = vA-1; 6x fused dpp-max; readlane; e=(v==gmax);
//   C/v cndmask; winner via ballot/ffs SALU-packed 8b x8 per u64.
// ---------------------------------------------------------------------------

constexpr int Bb = 256, Ll = 8192, DIMc = 256, NPAT = 64, HIST = 32, WINc = 8;
constexpr int Tt = Ll / WINc;   // 1024
constexpr int TC = 32;          // t-chunk
constexpr int NC = Tt / TC;     // 32 chunks
constexpr float CINV = 1.0f / 64.0f;

#define DPP_STAGE(m, ctrl, rmask)                                              \
  (m) = fmaxf((m), __int_as_float(__builtin_amdgcn_update_dpp(                 \
            __float_as_int(m), __float_as_int(m), (ctrl), (rmask), 0xF, false)))

#define DPP_ADDF(s, ctrl, rmask)                                               \
  do {                                                                         \
    int _si = __float_as_int(s);                                               \
    int _ti = __builtin_amdgcn_update_dpp(_si, _si, (ctrl), (rmask), 0xF, false); \
    (s) += __int_as_float(_ti);                                                \
  } while (0)

// one block per pattern p: W2[p,0..31] + bias2[p]
__global__ __launch_bounds__(256) void precompute_kernel(
    const float* __restrict__ conv_w, const float* __restrict__ conv_b,
    const float* __restrict__ keys_w, float* __restrict__ wsf) {
  __shared__ float part[8][32];
  __shared__ float bred[4];
  const int p = blockIdx.x;
  const int t = threadIdx.x;
  const int h = t & 31, g = t >> 5;
  const float* kwp = keys_w + (size_t)p * DIMc;

  float acc = 0.f;
#pragma unroll
  for (int dd = 0; dd < 32; ++dd) {
    int d = g * 32 + dd;
    acc = fmaf(kwp[d], conv_w[d * HIST + h], acc);
  }
  part[g][h] = acc;

  float bp = kwp[t] * conv_b[t];
#pragma unroll
  for (int off = 32; off; off >>= 1) bp += __shfl_down(bp, off);
  if ((t & 63) == 0) bred[t >> 6] = bp;
  __syncthreads();

  if (t < 32) {
    float s = 0.f;
#pragma unroll
    for (int gg = 0; gg < 8; ++gg) s += part[gg][t];
    wsf[(t >> 2) * (NPAT * 4) + p * 4 + (t & 3)] = s;  // float4-friendly
  } else if (t == 32) {
    wsf[NPAT * HIST + p] = (bred[0] + bred[1]) + (bred[2] + bred[3]);
  }
}

__global__ __launch_bounds__(256) void shaper_kernel(
    const float* __restrict__ x, const float* __restrict__ avg_init,
    const float* __restrict__ shapes_w, const float* __restrict__ wsf,
    float* __restrict__ out) {
  __shared__ __align__(16) float xpad[HIST - 1 + Ll + 1];
  __shared__ float scb[2][TC * NPAT];
  __shared__ unsigned long long idxp[NC * 4];  // 8 winners per u64
  __shared__ float shp[WINc * NPAT];

  const int b    = blockIdx.x;
  const int tid  = threadIdx.x;
  const int wid  = tid >> 6;
  const int lane = tid & 63;
  const float* xrow = x + (size_t)b * Ll;

  // ---- stage x (left-padded) + shapes into LDS ----
  if (tid < HIST - 1) xpad[tid] = 0.f;
  {
    const float4* xv4 = (const float4*)xrow;
#pragma unroll
    for (int k = 0; k < 8; ++k) {
      int i4 = k * 256 + tid;
      float4 v = xv4[i4];
      float* dst = xpad + HIST - 1 + i4 * 4;
      dst[0] = v.x; dst[1] = v.y; dst[2] = v.z; dst[3] = v.w;
    }
  }
  for (int i = tid; i < WINc * NPAT; i += 256) shp[i] = shapes_w[i];

  // ---- av0 via DPP-sum butterfly (all waves; validated R5/R8/R10) ----
  float av0;
  {
    float s = avg_init[(size_t)b * NPAT + lane];
    float t = s;
    DPP_ADDF(t, 0xB1, 0xF);
    DPP_ADDF(t, 0x4E, 0xF);
    DPP_ADDF(t, 0x141, 0xF);
    DPP_ADDF(t, 0x140, 0xF);
    DPP_ADDF(t, 0x142, 0xA);
    DPP_ADDF(t, 0x143, 0xC);   // lane63 = total
    float tot = __int_as_float(__builtin_amdgcn_readlane(__float_as_int(t), 63));
    av0 = s - tot * CINV;
  }

  // ---- per-role setup ----
  float4 w2v[8];
  float  b2 = 0.f;
  if (wid > 0) {
    const float4* w2g = (const float4*)wsf;
#pragma unroll
    for (int h4 = 0; h4 < 8; ++h4) w2v[h4] = w2g[h4 * 64 + lane];
    b2 = wsf[NPAT * HIST + lane];
  }
  __syncthreads();

  // fill chunk c: sb[t][p] = (relu6(score) - av0[p]) + tglob/64  (== U_t[p])
  auto fill = [&](int c, float* __restrict__ sb) {
    int base = c * TC;
    for (int tl = wid - 1; tl < TC; tl += 3) {
      int t = base + tl;
      const float4* xw = (const float4*)(xpad + t * WINc);  // 32B-aligned
      float acc = b2;
#pragma unroll
      for (int h4 = 0; h4 < 8; ++h4) {
        float4 xv = xw[h4];
        float4 wv = w2v[h4];
        acc = fmaf(xv.x, wv.x, acc);
        acc = fmaf(xv.y, wv.y, acc);
        acc = fmaf(xv.z, wv.z, acc);
        acc = fmaf(xv.w, wv.w, acc);
      }
      float sc = fminf(fmaxf(acc, 0.f), 6.f);
      sb[tl * NPAT + lane] = (sc - av0) + (float)t * CINV;
    }
  };

  // ---- scan state (wave 0): C = win count (starts 0), across chunks ----
  float C = 0.f;

  auto scan_chunk = [&](const float* __restrict__ sb, int cidx) {
    float U[TC];
#pragma unroll
    for (int i = 0; i < TC; ++i) U[i] = sb[i * NPAT + lane];
    unsigned long long pk0 = 0, pk1 = 0, pk2 = 0, pk3 = 0;
    float v = U[0] - C;
#pragma unroll
    for (int i = 0; i < TC; ++i) {
      float vA = 0.f, vB = 0.f;
      if (i + 1 < TC) { vA = U[i + 1] - C; vB = vA - 1.0f; }
      float m = v;
      DPP_STAGE(m, 0xB1, 0xF);   // xor1
      DPP_STAGE(m, 0x4E, 0xF);   // xor2
      DPP_STAGE(m, 0x141, 0xF);  // xor4 (row_half_mirror)
      DPP_STAGE(m, 0x140, 0xF);  // xor8 (row_mirror) -> row16 max
      DPP_STAGE(m, 0x142, 0xA);  // row_bcast15 -> rows 1,3
      DPP_STAGE(m, 0x143, 0xC);  // row_bcast31 -> rows 2,3; lane63 = gmax
      float gmax = __int_as_float(
          __builtin_amdgcn_readlane(__float_as_int(m), 63));
      bool e = (v == gmax);             // all-maximal (tie-free, R6-R10)
      float C1 = C + 1.0f;
      // off-cycle: first-index winner, SALU-packed (8 bits each)
      unsigned long long mk = __ballot(e);
      unsigned long long w = (unsigned long long)(__ffsll(mk) - 1);
      if (i < 8)       pk0 |= w << (8 * (i & 7));
      else if (i < 16) pk1 |= w << (8 * (i & 7));
      else if (i < 24) pk2 |= w << (8 * (i & 7));
      else             pk3 |= w << (8 * (i & 7));
      C = e ? C1 : C;
      if (i + 1 < TC) v = e ? vB : vA;
    }
    if (lane == 0) {
      idxp[cidx * 4 + 0] = pk0;
      idxp[cidx * 4 + 1] = pk1;
      idxp[cidx * 4 + 2] = pk2;
      idxp[cidx * 4 + 3] = pk3;
    }
  };

  // ---- pipeline: wave0 scans chunk c, waves1-3 fill chunk c+1 ----
  if (wid > 0) fill(0, scb[0]);
  __syncthreads();

  for (int c = 0; c < NC; ++c) {
    if (wid == 0) {
      scan_chunk(scb[c & 1], c);
    } else if (c + 1 < NC) {
      fill(c + 1, scb[(c + 1) & 1]);
    }
    __syncthreads();
  }

  // ---- epilogue: out[b,l] = relu(shapes[l&7, idx[l>>3]] - x[b,l]) ----
  float4* outv = (float4*)(out + (size_t)b * Ll);
#pragma unroll
  for (int k = 0; k < 8; ++k) {
    int i4 = k * 256 + tid;
    int l0 = i4 * 4;
    int t  = l0 >> 3;
    int w0 = l0 & 7;
    int p  = (int)((idxp[t >> 3] >> (8 * (t & 7))) & 63ull);
    float4 o;
    o.x = fmaxf(shp[(w0 + 0) * NPAT + p] - xpad[HIST - 1 + l0 + 0], 0.f);
    o.y = fmaxf(shp[(w0 + 1) * NPAT + p] - xpad[HIST - 1 + l0 + 1], 0.f);
    o.z = fmaxf(shp[(w0 + 2) * NPAT + p] - xpad[HIST - 1 + l0 + 2], 0.f);
    o.w = fmaxf(shp[(w0 + 3) * NPAT + p] - xpad[HIST - 1 + l0 + 3], 0.f);
    outv[i4] = o;
  }
}

extern "C" void kernel_launch(void* const* d_in, const int* in_sizes, int n_in,
                              void* d_out, int out_size, void* d_ws, size_t ws_size,
                              hipStream_t stream) {
  const float* x        = (const float*)d_in[0];
  const float* avg_init = (const float*)d_in[1];
  const float* conv_w   = (const float*)d_in[2];
  const float* conv_b   = (const float*)d_in[3];
  const float* keys_w   = (const float*)d_in[4];
  const float* shapes_w = (const float*)d_in[5];
  float* wsf = (float*)d_ws;

  precompute_kernel<<<NPAT, 256, 0, stream>>>(conv_w, conv_b, keys_w, wsf);
  shaper_kernel<<<Bb, 256, 0, stream>>>(x, avg_init, shapes_w, wsf,
                                        (float*)d_out);
}